// Round 8
// baseline (205.882 us; speedup 1.0000x reference)
//
#include <hip/hip_runtime.h>

// MoGeSampledLocalLoss: per-patch truncated robust affine depth alignment +
// smooth-L1 loss, global mean over valid patches.
//
// Structure: one patch per DPP ROW (16 lanes, 16 px/lane, 4 patches/wave);
// row reductions = 4 fused DPP row_ror adds (total lands in all 16 lanes).
// R8 theory: R5/R6/R7 (three different structures) all ~28us -> latency-
// exposure-bound with occupancy VGPR-capped at ~16-20 waves/CU (64 VGPRs of
// live pixel data + temps). R8 shrinks the live set to <=64 VGPR total:
//  - mask: 16 int regs -> 1-bit-per-pixel bitmask (built during load)
//  - wv[16] dropped; w recomputed in pass 2 (bit-identical: same inputs/ops)
//  - no prefetch loop (R7 proved neutral; it only inflates registers)
//  - __launch_bounds__(256, 8) -> 8 waves/EU = 32 waves/CU target
// History: R1-R4 pinned 43-47us by same-line atomics; R5 scatter -> ~29us;
// R6 instr cut, R7 prefetch -> both neutral. Harness fixed cost ~100us
// (256MB d_ws poison ~40us + input restores) not addressable from kernel.

#define WPB 4        // waves per 256-thread block
#define PPW 4        // patches per wave (one per DPP row)
#define MAXBLK 2048  // full cover: 16 patches/block at 32768 patches

// Full-wave sum -> wave-uniform scalar (DPP row_shr + row_bcast + readlane).
__device__ __forceinline__ float wredu(float v) {
#define DPP_ADD(ctrl)                                                        \
  v += __int_as_float(__builtin_amdgcn_update_dpp(                           \
      0, __float_as_int(v), (ctrl), 0xf, 0xf, true))
  DPP_ADD(0x111);  // row_shr:1
  DPP_ADD(0x112);  // row_shr:2
  DPP_ADD(0x114);  // row_shr:4
  DPP_ADD(0x118);  // row_shr:8
  DPP_ADD(0x142);  // row_bcast:15
  DPP_ADD(0x143);  // row_bcast:31
#undef DPP_ADD
  return __int_as_float(__builtin_amdgcn_readlane(__float_as_int(v), 63));
}

// Sum across the 16 lanes of each DPP row; EVERY lane of the row ends with
// the row total (rotation-add is a circulant reduction: spans 2,4,8,16).
__device__ __forceinline__ float rowredu(float v) {
#define DPP_ADD(ctrl)                                                        \
  v += __int_as_float(__builtin_amdgcn_update_dpp(                           \
      0, __float_as_int(v), (ctrl), 0xf, 0xf, true))
  DPP_ADD(0x121);  // row_ror:1
  DPP_ADD(0x122);  // row_ror:2
  DPP_ADD(0x124);  // row_ror:4
  DPP_ADD(0x128);  // row_ror:8
#undef DPP_ADD
  return v;
}

__device__ __forceinline__ float frcp(float x) {
  return __builtin_amdgcn_rcpf(x);   // ~1 ulp, 1 VALU instr
}

__global__ __launch_bounds__(256, 8) void moge_patch_kernel(
    const float* __restrict__ xg,   // pred_depth (B*N)
    const float* __restrict__ yg,   // gt_depth   (B*N)
    const int*   __restrict__ mg,   // mask       (B*N), 0/1
    const float* __restrict__ gsg,  // global_scale (B)
    const int*   __restrict__ pP,   // num_patches (device scalar)
    const int*   __restrict__ pK,   // patch_pixel_count (device scalar)
    int B,
    float* __restrict__ ws) {       // block b owns line ws[b*32 .. b*32+31]
  const int P = pP[0];
  const int K = pK[0];
  const int lane = threadIdx.x & 63;
  const int wib  = threadIdx.x >> 6;
  const int total_patches = B * P;
  const float invK = 1.0f / (float)K;

  float wloss = 0.f, wcnt = 0.f;    // per-lane accumulators

  if (K == 256) {
    // ------- fast path: patch-per-row, 16 pixels/lane, bitmask mask ---
    const int row = lane >> 4;       // 0..3 -> patch within wave
    const int col = lane & 15;       // lane within row
    const int poff = col * 16;       // this lane's 16-pixel chunk
    const int group_stride = gridDim.x * WPB * PPW;

    for (int pbase = (blockIdx.x * WPB + wib) * PPW; pbase < total_patches;
         pbase += group_stride) {
      const int patch = pbase + row;
      const bool row_ok = patch < total_patches;
      const long base = (row_ok ? (long)patch * 256L : 0L) + poff;

      // x,y stay in registers (32 VGPRs); mask collapses to 16 bits.
      float4 xa[4], ya[4];
      unsigned mbits = 0;
      #pragma unroll
      for (int j = 0; j < 4; ++j) {
        xa[j] = *(const float4*)(xg + base + 4 * j);
        ya[j] = *(const float4*)(yg + base + 4 * j);
        const int4 m4 = *(const int4*)(mg + base + 4 * j);
        mbits |= (m4.x ? 1u : 0u) << (4 * j);
        mbits |= (m4.y ? 2u : 0u) << (4 * j);
        mbits |= (m4.z ? 4u : 0u) << (4 * j);
        mbits |= (m4.w ? 8u : 0u) << (4 * j);
      }
      const float* xr = (const float*)xa;
      const float* yr = (const float*)ya;

      // -- pass 1: WLS sums (msum/symsum reduced with batch 2) ---------
      float sw = 0.f, swx = 0.f, swy = 0.f, swxx = 0.f, swxy = 0.f;
      float msum = 0.f, symsum = 0.f;
      #pragma unroll
      for (int i = 0; i < 16; ++i) {
        const float m = (mbits >> i) & 1u ? 1.f : 0.f;
        const float xx = xr[i], yy = yr[i];
        const float w = m * frcp(fmaxf(yy, 1e-5f));
        const float wx = w * xx;
        sw += w; swx += wx; swy = fmaf(w, yy, swy);
        swxx = fmaf(wx, xx, swxx); swxy = fmaf(wx, yy, swxy);
        msum += m; symsum = fmaf(m, yy, symsum);
      }
      sw = rowredu(sw); swx = rowredu(swx); swy = rowredu(swy);
      swxx = rowredu(swxx); swxy = rowredu(swxy);

      float det = sw * swxx - swx * swx;
      if (fabsf(det) < 1e-12f) det = 1e-12f;  // jnp.where -> +1e-12 any sign
      float rdet = frcp(det);
      const float s0 = (sw * swxy - swx * swy) * rdet;
      const float t0 = (swxx * swy - swx * swxy) * rdet;

      // -- pass 2: truncated refit; w recomputed (bit-identical) -------
      float sw2 = 0.f, swx2 = 0.f, swy2 = 0.f, swxx2 = 0.f, swxy2 = 0.f;
      #pragma unroll
      for (int i = 0; i < 16; ++i) {
        const float m = (mbits >> i) & 1u ? 1.f : 0.f;
        const float xx = xr[i], yy = yr[i];
        const float w = m * frcp(fmaxf(yy, 1e-5f));
        const float e = w * fabsf(fmaf(s0, xx, t0) - yy);
        const float w2 = (e < 1.0f) ? w : 0.f;  // TRUNC = 1.0, strict <
        const float w2x = w2 * xx;
        sw2 += w2; swx2 += w2x; swy2 = fmaf(w2, yy, swy2);
        swxx2 = fmaf(w2x, xx, swxx2); swxy2 = fmaf(w2x, yy, swxy2);
      }
      sw2 = rowredu(sw2); swx2 = rowredu(swx2); swy2 = rowredu(swy2);
      swxx2 = rowredu(swxx2); swxy2 = rowredu(swxy2);
      msum = rowredu(msum); symsum = rowredu(symsum);

      if (sw2 > 1e-8f) {  // sum(w2)==sw2; else fall back to pass-1 sums
        sw = sw2; swx = swx2; swy = swy2; swxx = swxx2; swxy = swxy2;
      }
      det = sw * swxx - swx * swx;
      if (fabsf(det) < 1e-12f) det = 1e-12f;
      rdet = frcp(det);
      const float s = (sw * swxy - swx * swy) * rdet;
      const float t = (swxx * swy - swx * swxy) * rdet;

      // -- pass 3: smooth-L1 patch loss --------------------------------
      const float mean_depth =
          (msum > 0.f) ? (symsum * frcp(fmaxf(msum, 1.f))) : 1.f;
      const float yfloor = 0.1f * mean_depth;

      float lsum = 0.f;
      #pragma unroll
      for (int i = 0; i < 16; ++i) {
        const float m = (mbits >> i) & 1u ? 1.f : 0.f;
        const float pw = m * frcp(fmaxf(yr[i], yfloor));
        const float err = fabsf(fmaf(s, xr[i], t) - yr[i]) * pw;
        // BETA = 0.1: err<0.1 ? 0.5*err^2/0.1 : err-0.05
        lsum += (err < 0.1f) ? (5.0f * err * err) : (err - 0.05f);
      }
      const float patch_loss = rowredu(lsum) * invK;

      // -- validity (row-uniform), accumulate on col==0 ----------------
      const int pidx = row_ok ? patch : (total_patches - 1);
      const float gs = gsg[(unsigned)pidx / (unsigned)P];
      const float ratio = s * frcp(fmaxf(gs, 1e-12f));
      const bool gs_ok = (gs > 0.f) ? (ratio >= 0.1f && ratio <= 10.0f) : true;
      const bool valid = (msum * invK >= 0.3f) && (s > 0.f) && gs_ok;

      if (col == 0 && row_ok && valid) { wloss += patch_loss; wcnt += 1.f; }
    }
  } else {
    // ------- generic path (any K): wave-per-patch ---------------------
    const int wave_stride = gridDim.x * WPB;
    for (int patch = blockIdx.x * WPB + wib; patch < total_patches;
         patch += wave_stride) {
      const long base = (long)patch * (long)K;
      const float* xp = xg + base;
      const float* yp = yg + base;
      const int*   mp = mg + base;

      float sw = 0.f, swx = 0.f, swy = 0.f, swxx = 0.f, swxy = 0.f;
      float msum = 0.f, symsum = 0.f;
      for (int j = lane; j < K; j += 64) {
        const float m = mp[j] ? 1.f : 0.f;
        const float xx = xp[j], yy = yp[j];
        const float w = m * frcp(fmaxf(yy, 1e-5f));
        const float wx = w * xx;
        sw += w; swx += wx; swy = fmaf(w, yy, swy);
        swxx = fmaf(wx, xx, swxx); swxy = fmaf(wx, yy, swxy);
        msum += m; symsum = fmaf(m, yy, symsum);
      }
      sw = wredu(sw); swx = wredu(swx); swy = wredu(swy);
      swxx = wredu(swxx); swxy = wredu(swxy);
      msum = wredu(msum); symsum = wredu(symsum);

      float det = sw * swxx - swx * swx;
      if (fabsf(det) < 1e-12f) det = 1e-12f;
      float rdet = frcp(det);
      const float s0 = (sw * swxy - swx * swy) * rdet;
      const float t0 = (swxx * swy - swx * swxy) * rdet;

      float sw2 = 0.f, swx2 = 0.f, swy2 = 0.f, swxx2 = 0.f, swxy2 = 0.f;
      for (int j = lane; j < K; j += 64) {
        const float m = mp[j] ? 1.f : 0.f;
        const float xx = xp[j], yy = yp[j];
        const float w = m * frcp(fmaxf(yy, 1e-5f));
        const float e = w * fabsf(fmaf(s0, xx, t0) - yy);
        const float w2 = (e < 1.0f) ? w : 0.f;
        const float w2x = w2 * xx;
        sw2 += w2; swx2 += w2x; swy2 = fmaf(w2, yy, swy2);
        swxx2 = fmaf(w2x, xx, swxx2); swxy2 = fmaf(w2x, yy, swxy2);
      }
      sw2 = wredu(sw2); swx2 = wredu(swx2); swy2 = wredu(swy2);
      swxx2 = wredu(swxx2); swxy2 = wredu(swxy2);

      if (sw2 > 1e-8f) {
        sw = sw2; swx = swx2; swy = swy2; swxx = swxx2; swxy = swxy2;
      }
      det = sw * swxx - swx * swx;
      if (fabsf(det) < 1e-12f) det = 1e-12f;
      rdet = frcp(det);
      const float s = (sw * swxy - swx * swy) * rdet;
      const float t = (swxx * swy - swx * swxy) * rdet;

      const float mean_depth =
          (msum > 0.f) ? (symsum * frcp(fmaxf(msum, 1.f))) : 1.f;
      const float yfloor = 0.1f * mean_depth;

      float lsum = 0.f;
      for (int j = lane; j < K; j += 64) {
        const float m = mp[j] ? 1.f : 0.f;
        const float xx = xp[j], yy = yp[j];
        const float pw = m * frcp(fmaxf(yy, yfloor));
        const float err = fabsf(fmaf(s, xx, t) - yy) * pw;
        lsum += (err < 0.1f) ? (5.0f * err * err) : (err - 0.05f);
      }
      const float patch_loss = wredu(lsum) * invK;

      const float gs = gsg[(unsigned)patch / (unsigned)P];
      const float ratio = s * frcp(fmaxf(gs, 1e-12f));
      const bool gs_ok = (gs > 0.f) ? (ratio >= 0.1f && ratio <= 10.0f) : true;
      const bool valid = (msum * invK >= 0.3f) && (s > 0.f) && gs_ok;

      if (lane == 0 && valid) { wloss += patch_loss; wcnt += 1.f; }
    }
  }

  // ---- wave reduce -> block reduce (LDS) -> plain store to OWN line --
  wloss = wredu(wloss);
  wcnt  = wredu(wcnt);
  __shared__ float sl[WPB], sc[WPB];
  if (lane == 0) { sl[wib] = wloss; sc[wib] = wcnt; }
  __syncthreads();
  if (threadIdx.x == 0) {
    float bl = 0.f, bc = 0.f;
    #pragma unroll
    for (int i = 0; i < WPB; ++i) { bl += sl[i]; bc += sc[i]; }
    // private 128-B line per block: no zeroing, no atomics needed.
    ws[blockIdx.x * 32]     = bl;
    ws[blockIdx.x * 32 + 1] = bc;
  }
}

__global__ __launch_bounds__(256) void finalize_kernel(
    const float* __restrict__ ws, float* __restrict__ out, int nblocks) {
  const int lane = threadIdx.x & 63;
  const int wib  = threadIdx.x >> 6;
  float l = 0.f, c = 0.f;
  for (int i = threadIdx.x; i < nblocks; i += 256) {
    l += ws[i * 32];
    c += ws[i * 32 + 1];
  }
  l = wredu(l); c = wredu(c);
  __shared__ float sl[4], sc[4];
  if (lane == 0) { sl[wib] = l; sc[wib] = c; }
  __syncthreads();
  if (threadIdx.x == 0) {
    const float L = sl[0] + sl[1] + sl[2] + sl[3];
    const float C = sc[0] + sc[1] + sc[2] + sc[3];
    out[0] = (C > 0.f) ? (L / fmaxf(C, 1.f)) : 0.f;
  }
}

extern "C" void kernel_launch(void* const* d_in, const int* in_sizes, int n_in,
                              void* d_out, int out_size, void* d_ws, size_t ws_size,
                              hipStream_t stream) {
  const float* pred = (const float*)d_in[0];
  const float* gt   = (const float*)d_in[1];
  const int*   mask = (const int*)d_in[2];
  const float* gs   = (const float*)d_in[3];
  const int*   pP   = (const int*)d_in[4];
  const int*   pK   = (const int*)d_in[5];
  const int B = in_sizes[3];
  const long total_pixels = (long)in_sizes[0];
  float* ws = (float*)d_ws;

  // grid sized for K=256: 16 patches per block (4 waves x 4 rows)
  long est_patches = total_pixels / 256;
  long blocks = (est_patches + WPB * PPW - 1) / (WPB * PPW);
  if (blocks < 1) blocks = 1;
  if (blocks > MAXBLK) blocks = MAXBLK;
  moge_patch_kernel<<<(int)blocks, 256, 0, stream>>>(pred, gt, mask, gs, pP,
                                                     pK, B, ws);
  finalize_kernel<<<1, 256, 0, stream>>>(ws, (float*)d_out, (int)blocks);
}

// Round 10
// 144.520 us; speedup vs baseline: 1.4246x; 1.4246x over previous
//
#include <hip/hip_runtime.h>

// MoGeSampledLocalLoss: per-patch truncated robust affine depth alignment +
// smooth-L1 loss, global mean over valid patches.
//
// Structure: one patch per DPP ROW (16 lanes, 16 px/lane, 4 patches/wave);
// row reductions = 4 fused DPP row_ror adds (total lands in all 16 lanes).
// R10 = R9 with the compile fix: __builtin_nontemporal_load requires native
// clang vectors (ext_vector_type), not HIP_vector_type structs.
//  - launch_bounds plain 256 (R8's (256,8) forced VGPR=32 -> scratch spill,
//    WRITE_SIZE 0.3->180MB, 105us regression)
//  - pixel data as explicit vector components (nothing to demote to scratch)
//  - NONTEMPORAL loads for x/y/mask: zero-reuse 100MB stream, nt policy
//    avoids L2 allocation thrash
// History: R1-R4 pinned 43-47us by same-line device atomics; R5 scatter
// slots -> ~29us; R6 instr cut (row-DPP) neutral; R7 prefetch neutral;
// R8 occupancy-force -> spill regression. Kernel ~28us = 100MB @ ~3.6TB/s
// composite (49MB HBM + L3 hits); VALU issue only ~3.4us. Harness fixed
// cost ~100us (256MB d_ws poison fill ~40us + input restores).

#define WPB 4        // waves per 256-thread block
#define PPW 4        // patches per wave (one per DPP row)
#define MAXBLK 2048  // full cover: 16 patches/block at 32768 patches

typedef float  vf4 __attribute__((ext_vector_type(4)));
typedef int    vi4 __attribute__((ext_vector_type(4)));

// Full-wave sum -> wave-uniform scalar (DPP row_shr + row_bcast + readlane).
__device__ __forceinline__ float wredu(float v) {
#define DPP_ADD(ctrl)                                                        \
  v += __int_as_float(__builtin_amdgcn_update_dpp(                           \
      0, __float_as_int(v), (ctrl), 0xf, 0xf, true))
  DPP_ADD(0x111);  // row_shr:1
  DPP_ADD(0x112);  // row_shr:2
  DPP_ADD(0x114);  // row_shr:4
  DPP_ADD(0x118);  // row_shr:8
  DPP_ADD(0x142);  // row_bcast:15
  DPP_ADD(0x143);  // row_bcast:31
#undef DPP_ADD
  return __int_as_float(__builtin_amdgcn_readlane(__float_as_int(v), 63));
}

// Sum across the 16 lanes of each DPP row; EVERY lane of the row ends with
// the row total (rotation-add is a circulant reduction: spans 2,4,8,16).
__device__ __forceinline__ float rowredu(float v) {
#define DPP_ADD(ctrl)                                                        \
  v += __int_as_float(__builtin_amdgcn_update_dpp(                           \
      0, __float_as_int(v), (ctrl), 0xf, 0xf, true))
  DPP_ADD(0x121);  // row_ror:1
  DPP_ADD(0x122);  // row_ror:2
  DPP_ADD(0x124);  // row_ror:4
  DPP_ADD(0x128);  // row_ror:8
#undef DPP_ADD
  return v;
}

__device__ __forceinline__ float frcp(float x) {
  return __builtin_amdgcn_rcpf(x);   // ~1 ulp, 1 VALU instr
}

__global__ __launch_bounds__(256) void moge_patch_kernel(
    const float* __restrict__ xg,   // pred_depth (B*N)
    const float* __restrict__ yg,   // gt_depth   (B*N)
    const int*   __restrict__ mg,   // mask       (B*N), 0/1
    const float* __restrict__ gsg,  // global_scale (B)
    const int*   __restrict__ pP,   // num_patches (device scalar)
    const int*   __restrict__ pK,   // patch_pixel_count (device scalar)
    int B,
    float* __restrict__ ws) {       // block b owns line ws[b*32 .. b*32+31]
  const int P = pP[0];
  const int K = pK[0];
  const int lane = threadIdx.x & 63;
  const int wib  = threadIdx.x >> 6;
  const int total_patches = B * P;
  const float invK = 1.0f / (float)K;

  float wloss = 0.f, wcnt = 0.f;    // per-lane accumulators

  if (K == 256) {
    // ------- fast path: patch-per-row, 16 pixels/lane -----------------
    const int row = lane >> 4;       // 0..3 -> patch within wave
    const int col = lane & 15;       // lane within row
    const int poff = col * 16;       // this lane's 16-pixel chunk
    const int group_stride = gridDim.x * WPB * PPW;

    for (int pbase = (blockIdx.x * WPB + wib) * PPW; pbase < total_patches;
         pbase += group_stride) {
      const int patch = pbase + row;
      const bool row_ok = patch < total_patches;
      const long base = (row_ok ? (long)patch * 256L : 0L) + poff;

      // x,y in registers as native vectors (32 VGPRs); mask -> 16 bits.
      // Nontemporal: zero-reuse stream, don't allocate in L2.
      vf4 xa0 = __builtin_nontemporal_load((const vf4*)(xg + base));
      vf4 xa1 = __builtin_nontemporal_load((const vf4*)(xg + base + 4));
      vf4 xa2 = __builtin_nontemporal_load((const vf4*)(xg + base + 8));
      vf4 xa3 = __builtin_nontemporal_load((const vf4*)(xg + base + 12));
      vf4 ya0 = __builtin_nontemporal_load((const vf4*)(yg + base));
      vf4 ya1 = __builtin_nontemporal_load((const vf4*)(yg + base + 4));
      vf4 ya2 = __builtin_nontemporal_load((const vf4*)(yg + base + 8));
      vf4 ya3 = __builtin_nontemporal_load((const vf4*)(yg + base + 12));
      unsigned mbits = 0;
      {
        const vi4 m0 = __builtin_nontemporal_load((const vi4*)(mg + base));
        const vi4 m1 = __builtin_nontemporal_load((const vi4*)(mg + base + 4));
        const vi4 m2 = __builtin_nontemporal_load((const vi4*)(mg + base + 8));
        const vi4 m3 = __builtin_nontemporal_load((const vi4*)(mg + base + 12));
        mbits |= (m0.x ? 0x0001u : 0u) | (m0.y ? 0x0002u : 0u) |
                 (m0.z ? 0x0004u : 0u) | (m0.w ? 0x0008u : 0u) |
                 (m1.x ? 0x0010u : 0u) | (m1.y ? 0x0020u : 0u) |
                 (m1.z ? 0x0040u : 0u) | (m1.w ? 0x0080u : 0u) |
                 (m2.x ? 0x0100u : 0u) | (m2.y ? 0x0200u : 0u) |
                 (m2.z ? 0x0400u : 0u) | (m2.w ? 0x0800u : 0u) |
                 (m3.x ? 0x1000u : 0u) | (m3.y ? 0x2000u : 0u) |
                 (m3.z ? 0x4000u : 0u) | (m3.w ? 0x8000u : 0u);
      }

      // -- pass 1: WLS sums ------------------------------------------
      float sw = 0.f, swx = 0.f, swy = 0.f, swxx = 0.f, swxy = 0.f;
      float msum = 0.f, symsum = 0.f;
#define P1(xx_, yy_, bit_)                                                   \
  {                                                                          \
    const float m = (mbits >> (bit_)) & 1u ? 1.f : 0.f;                      \
    const float xx = (xx_), yy = (yy_);                                      \
    const float w = m * frcp(fmaxf(yy, 1e-5f));                              \
    const float wx = w * xx;                                                 \
    sw += w; swx += wx; swy = fmaf(w, yy, swy);                              \
    swxx = fmaf(wx, xx, swxx); swxy = fmaf(wx, yy, swxy);                    \
    msum += m; symsum = fmaf(m, yy, symsum);                                 \
  }
      P1(xa0.x, ya0.x, 0)  P1(xa0.y, ya0.y, 1)
      P1(xa0.z, ya0.z, 2)  P1(xa0.w, ya0.w, 3)
      P1(xa1.x, ya1.x, 4)  P1(xa1.y, ya1.y, 5)
      P1(xa1.z, ya1.z, 6)  P1(xa1.w, ya1.w, 7)
      P1(xa2.x, ya2.x, 8)  P1(xa2.y, ya2.y, 9)
      P1(xa2.z, ya2.z, 10) P1(xa2.w, ya2.w, 11)
      P1(xa3.x, ya3.x, 12) P1(xa3.y, ya3.y, 13)
      P1(xa3.z, ya3.z, 14) P1(xa3.w, ya3.w, 15)
#undef P1
      sw = rowredu(sw); swx = rowredu(swx); swy = rowredu(swy);
      swxx = rowredu(swxx); swxy = rowredu(swxy);

      float det = sw * swxx - swx * swx;
      if (fabsf(det) < 1e-12f) det = 1e-12f;  // jnp.where -> +1e-12 any sign
      float rdet = frcp(det);
      const float s0 = (sw * swxy - swx * swy) * rdet;
      const float t0 = (swxx * swy - swx * swxy) * rdet;

      // -- pass 2: truncated refit; w recomputed (bit-identical) -------
      float sw2 = 0.f, swx2 = 0.f, swy2 = 0.f, swxx2 = 0.f, swxy2 = 0.f;
#define P2(xx_, yy_, bit_)                                                   \
  {                                                                          \
    const float m = (mbits >> (bit_)) & 1u ? 1.f : 0.f;                      \
    const float xx = (xx_), yy = (yy_);                                      \
    const float w = m * frcp(fmaxf(yy, 1e-5f));                              \
    const float e = w * fabsf(fmaf(s0, xx, t0) - yy);                        \
    const float w2 = (e < 1.0f) ? w : 0.f;                                   \
    const float w2x = w2 * xx;                                               \
    sw2 += w2; swx2 += w2x; swy2 = fmaf(w2, yy, swy2);                       \
    swxx2 = fmaf(w2x, xx, swxx2); swxy2 = fmaf(w2x, yy, swxy2);              \
  }
      P2(xa0.x, ya0.x, 0)  P2(xa0.y, ya0.y, 1)
      P2(xa0.z, ya0.z, 2)  P2(xa0.w, ya0.w, 3)
      P2(xa1.x, ya1.x, 4)  P2(xa1.y, ya1.y, 5)
      P2(xa1.z, ya1.z, 6)  P2(xa1.w, ya1.w, 7)
      P2(xa2.x, ya2.x, 8)  P2(xa2.y, ya2.y, 9)
      P2(xa2.z, ya2.z, 10) P2(xa2.w, ya2.w, 11)
      P2(xa3.x, ya3.x, 12) P2(xa3.y, ya3.y, 13)
      P2(xa3.z, ya3.z, 14) P2(xa3.w, ya3.w, 15)
#undef P2
      sw2 = rowredu(sw2); swx2 = rowredu(swx2); swy2 = rowredu(swy2);
      swxx2 = rowredu(swxx2); swxy2 = rowredu(swxy2);
      msum = rowredu(msum); symsum = rowredu(symsum);

      if (sw2 > 1e-8f) {  // sum(w2)==sw2; else fall back to pass-1 sums
        sw = sw2; swx = swx2; swy = swy2; swxx = swxx2; swxy = swxy2;
      }
      det = sw * swxx - swx * swx;
      if (fabsf(det) < 1e-12f) det = 1e-12f;
      rdet = frcp(det);
      const float s = (sw * swxy - swx * swy) * rdet;
      const float t = (swxx * swy - swx * swxy) * rdet;

      // -- pass 3: smooth-L1 patch loss --------------------------------
      const float mean_depth =
          (msum > 0.f) ? (symsum * frcp(fmaxf(msum, 1.f))) : 1.f;
      const float yfloor = 0.1f * mean_depth;

      float lsum = 0.f;
#define P3(xx_, yy_, bit_)                                                   \
  {                                                                          \
    const float m = (mbits >> (bit_)) & 1u ? 1.f : 0.f;                      \
    const float pw = m * frcp(fmaxf((yy_), yfloor));                         \
    const float err = fabsf(fmaf(s, (xx_), t) - (yy_)) * pw;                 \
    lsum += (err < 0.1f) ? (5.0f * err * err) : (err - 0.05f);               \
  }
      P3(xa0.x, ya0.x, 0)  P3(xa0.y, ya0.y, 1)
      P3(xa0.z, ya0.z, 2)  P3(xa0.w, ya0.w, 3)
      P3(xa1.x, ya1.x, 4)  P3(xa1.y, ya1.y, 5)
      P3(xa1.z, ya1.z, 6)  P3(xa1.w, ya1.w, 7)
      P3(xa2.x, ya2.x, 8)  P3(xa2.y, ya2.y, 9)
      P3(xa2.z, ya2.z, 10) P3(xa2.w, ya2.w, 11)
      P3(xa3.x, ya3.x, 12) P3(xa3.y, ya3.y, 13)
      P3(xa3.z, ya3.z, 14) P3(xa3.w, ya3.w, 15)
#undef P3
      const float patch_loss = rowredu(lsum) * invK;

      // -- validity (row-uniform), accumulate on col==0 ----------------
      const int pidx = row_ok ? patch : (total_patches - 1);
      const float gs = gsg[(unsigned)pidx / (unsigned)P];
      const float ratio = s * frcp(fmaxf(gs, 1e-12f));
      const bool gs_ok = (gs > 0.f) ? (ratio >= 0.1f && ratio <= 10.0f) : true;
      const bool valid = (msum * invK >= 0.3f) && (s > 0.f) && gs_ok;

      if (col == 0 && row_ok && valid) { wloss += patch_loss; wcnt += 1.f; }
    }
  } else {
    // ------- generic path (any K): wave-per-patch ---------------------
    const int wave_stride = gridDim.x * WPB;
    for (int patch = blockIdx.x * WPB + wib; patch < total_patches;
         patch += wave_stride) {
      const long base = (long)patch * (long)K;
      const float* xp = xg + base;
      const float* yp = yg + base;
      const int*   mp = mg + base;

      float sw = 0.f, swx = 0.f, swy = 0.f, swxx = 0.f, swxy = 0.f;
      float msum = 0.f, symsum = 0.f;
      for (int j = lane; j < K; j += 64) {
        const float m = mp[j] ? 1.f : 0.f;
        const float xx = xp[j], yy = yp[j];
        const float w = m * frcp(fmaxf(yy, 1e-5f));
        const float wx = w * xx;
        sw += w; swx += wx; swy = fmaf(w, yy, swy);
        swxx = fmaf(wx, xx, swxx); swxy = fmaf(wx, yy, swxy);
        msum += m; symsum = fmaf(m, yy, symsum);
      }
      sw = wredu(sw); swx = wredu(swx); swy = wredu(swy);
      swxx = wredu(swxx); swxy = wredu(swxy);
      msum = wredu(msum); symsum = wredu(symsum);

      float det = sw * swxx - swx * swx;
      if (fabsf(det) < 1e-12f) det = 1e-12f;
      float rdet = frcp(det);
      const float s0 = (sw * swxy - swx * swy) * rdet;
      const float t0 = (swxx * swy - swx * swxy) * rdet;

      float sw2 = 0.f, swx2 = 0.f, swy2 = 0.f, swxx2 = 0.f, swxy2 = 0.f;
      for (int j = lane; j < K; j += 64) {
        const float m = mp[j] ? 1.f : 0.f;
        const float xx = xp[j], yy = yp[j];
        const float w = m * frcp(fmaxf(yy, 1e-5f));
        const float e = w * fabsf(fmaf(s0, xx, t0) - yy);
        const float w2 = (e < 1.0f) ? w : 0.f;
        const float w2x = w2 * xx;
        sw2 += w2; swx2 += w2x; swy2 = fmaf(w2, yy, swy2);
        swxx2 = fmaf(w2x, xx, swxx2); swxy2 = fmaf(w2x, yy, swxy2);
      }
      sw2 = wredu(sw2); swx2 = wredu(swx2); swy2 = wredu(swy2);
      swxx2 = wredu(swxx2); swxy2 = wredu(swxy2);

      if (sw2 > 1e-8f) {
        sw = sw2; swx = swx2; swy = swy2; swxx = swxx2; swxy = swxy2;
      }
      det = sw * swxx - swx * swx;
      if (fabsf(det) < 1e-12f) det = 1e-12f;
      rdet = frcp(det);
      const float s = (sw * swxy - swx * swy) * rdet;
      const float t = (swxx * swy - swx * swxy) * rdet;

      const float mean_depth =
          (msum > 0.f) ? (symsum * frcp(fmaxf(msum, 1.f))) : 1.f;
      const float yfloor = 0.1f * mean_depth;

      float lsum = 0.f;
      for (int j = lane; j < K; j += 64) {
        const float m = mp[j] ? 1.f : 0.f;
        const float xx = xp[j], yy = yp[j];
        const float pw = m * frcp(fmaxf(yy, yfloor));
        const float err = fabsf(fmaf(s, xx, t) - yy) * pw;
        lsum += (err < 0.1f) ? (5.0f * err * err) : (err - 0.05f);
      }
      const float patch_loss = wredu(lsum) * invK;

      const float gs = gsg[(unsigned)patch / (unsigned)P];
      const float ratio = s * frcp(fmaxf(gs, 1e-12f));
      const bool gs_ok = (gs > 0.f) ? (ratio >= 0.1f && ratio <= 10.0f) : true;
      const bool valid = (msum * invK >= 0.3f) && (s > 0.f) && gs_ok;

      if (lane == 0 && valid) { wloss += patch_loss; wcnt += 1.f; }
    }
  }

  // ---- wave reduce -> block reduce (LDS) -> plain store to OWN line --
  wloss = wredu(wloss);
  wcnt  = wredu(wcnt);
  __shared__ float sl[WPB], sc[WPB];
  if (lane == 0) { sl[wib] = wloss; sc[wib] = wcnt; }
  __syncthreads();
  if (threadIdx.x == 0) {
    float bl = 0.f, bc = 0.f;
    #pragma unroll
    for (int i = 0; i < WPB; ++i) { bl += sl[i]; bc += sc[i]; }
    // private 128-B line per block: no zeroing, no atomics needed.
    ws[blockIdx.x * 32]     = bl;
    ws[blockIdx.x * 32 + 1] = bc;
  }
}

__global__ __launch_bounds__(256) void finalize_kernel(
    const float* __restrict__ ws, float* __restrict__ out, int nblocks) {
  const int lane = threadIdx.x & 63;
  const int wib  = threadIdx.x >> 6;
  float l = 0.f, c = 0.f;
  for (int i = threadIdx.x; i < nblocks; i += 256) {
    l += ws[i * 32];
    c += ws[i * 32 + 1];
  }
  l = wredu(l); c = wredu(c);
  __shared__ float sl[4], sc[4];
  if (lane == 0) { sl[wib] = l; sc[wib] = c; }
  __syncthreads();
  if (threadIdx.x == 0) {
    const float L = sl[0] + sl[1] + sl[2] + sl[3];
    const float C = sc[0] + sc[1] + sc[2] + sc[3];
    out[0] = (C > 0.f) ? (L / fmaxf(C, 1.f)) : 0.f;
  }
}

extern "C" void kernel_launch(void* const* d_in, const int* in_sizes, int n_in,
                              void* d_out, int out_size, void* d_ws, size_t ws_size,
                              hipStream_t stream) {
  const float* pred = (const float*)d_in[0];
  const float* gt   = (const float*)d_in[1];
  const int*   mask = (const int*)d_in[2];
  const float* gs   = (const float*)d_in[3];
  const int*   pP   = (const int*)d_in[4];
  const int*   pK   = (const int*)d_in[5];
  const int B = in_sizes[3];
  const long total_pixels = (long)in_sizes[0];
  float* ws = (float*)d_ws;

  // grid sized for K=256: 16 patches per block (4 waves x 4 rows)
  long est_patches = total_pixels / 256;
  long blocks = (est_patches + WPB * PPW - 1) / (WPB * PPW);
  if (blocks < 1) blocks = 1;
  if (blocks > MAXBLK) blocks = MAXBLK;
  moge_patch_kernel<<<(int)blocks, 256, 0, stream>>>(pred, gt, mask, gs, pP,
                                                     pK, B, ws);
  finalize_kernel<<<1, 256, 0, stream>>>(ws, (float*)d_out, (int)blocks);
}

// Round 11
// 132.116 us; speedup vs baseline: 1.5583x; 1.0939x over previous
//
#include <hip/hip_runtime.h>

// MoGeSampledLocalLoss: per-patch truncated robust affine depth alignment +
// smooth-L1 loss, global mean over valid patches.
//
// Structure: one patch per DPP ROW (16 lanes, 16 px/lane, 4 patches/wave);
// row reductions = 4 fused DPP row_ror adds (total lands in all 16 lanes).
// R11 = R10 with PLAIN cached loads (revert of nontemporal): the harness
// restores inputs before every replay, so x/y/mask are L2/L3-warm; nt
// bypassed cache allocation and turned warm hits into long-path reads
// (total 128 -> 144.5us). Plain loads restore the warm path.
// Decision log: R1-R4 pinned 43-47us by 65k same-line device atomics ->
// R5 per-block scatter slots (~29us kernel); R6 row-DPP instr cut neutral;
// R7 prefetch neutral; R8 launch_bounds(256,8) VGPR=32 spill regression
// (WRITE 0.3->180MB); R10 nt-loads regression (cache bypass). Main kernel
// ~28us = ~100MB mixed L3/HBM traffic; VALU issue ~3.4us. Harness fixed
// cost ~100us (256MB d_ws poison fill ~40us + input restores).

#define WPB 4        // waves per 256-thread block
#define PPW 4        // patches per wave (one per DPP row)
#define MAXBLK 2048  // full cover: 16 patches/block at 32768 patches

typedef float  vf4 __attribute__((ext_vector_type(4)));
typedef int    vi4 __attribute__((ext_vector_type(4)));

// Full-wave sum -> wave-uniform scalar (DPP row_shr + row_bcast + readlane).
__device__ __forceinline__ float wredu(float v) {
#define DPP_ADD(ctrl)                                                        \
  v += __int_as_float(__builtin_amdgcn_update_dpp(                           \
      0, __float_as_int(v), (ctrl), 0xf, 0xf, true))
  DPP_ADD(0x111);  // row_shr:1
  DPP_ADD(0x112);  // row_shr:2
  DPP_ADD(0x114);  // row_shr:4
  DPP_ADD(0x118);  // row_shr:8
  DPP_ADD(0x142);  // row_bcast:15
  DPP_ADD(0x143);  // row_bcast:31
#undef DPP_ADD
  return __int_as_float(__builtin_amdgcn_readlane(__float_as_int(v), 63));
}

// Sum across the 16 lanes of each DPP row; EVERY lane of the row ends with
// the row total (rotation-add is a circulant reduction: spans 2,4,8,16).
__device__ __forceinline__ float rowredu(float v) {
#define DPP_ADD(ctrl)                                                        \
  v += __int_as_float(__builtin_amdgcn_update_dpp(                           \
      0, __float_as_int(v), (ctrl), 0xf, 0xf, true))
  DPP_ADD(0x121);  // row_ror:1
  DPP_ADD(0x122);  // row_ror:2
  DPP_ADD(0x124);  // row_ror:4
  DPP_ADD(0x128);  // row_ror:8
#undef DPP_ADD
  return v;
}

__device__ __forceinline__ float frcp(float x) {
  return __builtin_amdgcn_rcpf(x);   // ~1 ulp, 1 VALU instr
}

__global__ __launch_bounds__(256) void moge_patch_kernel(
    const float* __restrict__ xg,   // pred_depth (B*N)
    const float* __restrict__ yg,   // gt_depth   (B*N)
    const int*   __restrict__ mg,   // mask       (B*N), 0/1
    const float* __restrict__ gsg,  // global_scale (B)
    const int*   __restrict__ pP,   // num_patches (device scalar)
    const int*   __restrict__ pK,   // patch_pixel_count (device scalar)
    int B,
    float* __restrict__ ws) {       // block b owns line ws[b*32 .. b*32+31]
  const int P = pP[0];
  const int K = pK[0];
  const int lane = threadIdx.x & 63;
  const int wib  = threadIdx.x >> 6;
  const int total_patches = B * P;
  const float invK = 1.0f / (float)K;

  float wloss = 0.f, wcnt = 0.f;    // per-lane accumulators

  if (K == 256) {
    // ------- fast path: patch-per-row, 16 pixels/lane -----------------
    const int row = lane >> 4;       // 0..3 -> patch within wave
    const int col = lane & 15;       // lane within row
    const int poff = col * 16;       // this lane's 16-pixel chunk
    const int group_stride = gridDim.x * WPB * PPW;

    for (int pbase = (blockIdx.x * WPB + wib) * PPW; pbase < total_patches;
         pbase += group_stride) {
      const int patch = pbase + row;
      const bool row_ok = patch < total_patches;
      const long base = (row_ok ? (long)patch * 256L : 0L) + poff;

      // x,y in registers as native vectors (32 VGPRs); mask -> 16 bits.
      vf4 xa0 = *(const vf4*)(xg + base);
      vf4 xa1 = *(const vf4*)(xg + base + 4);
      vf4 xa2 = *(const vf4*)(xg + base + 8);
      vf4 xa3 = *(const vf4*)(xg + base + 12);
      vf4 ya0 = *(const vf4*)(yg + base);
      vf4 ya1 = *(const vf4*)(yg + base + 4);
      vf4 ya2 = *(const vf4*)(yg + base + 8);
      vf4 ya3 = *(const vf4*)(yg + base + 12);
      unsigned mbits = 0;
      {
        const vi4 m0 = *(const vi4*)(mg + base);
        const vi4 m1 = *(const vi4*)(mg + base + 4);
        const vi4 m2 = *(const vi4*)(mg + base + 8);
        const vi4 m3 = *(const vi4*)(mg + base + 12);
        mbits |= (m0.x ? 0x0001u : 0u) | (m0.y ? 0x0002u : 0u) |
                 (m0.z ? 0x0004u : 0u) | (m0.w ? 0x0008u : 0u) |
                 (m1.x ? 0x0010u : 0u) | (m1.y ? 0x0020u : 0u) |
                 (m1.z ? 0x0040u : 0u) | (m1.w ? 0x0080u : 0u) |
                 (m2.x ? 0x0100u : 0u) | (m2.y ? 0x0200u : 0u) |
                 (m2.z ? 0x0400u : 0u) | (m2.w ? 0x0800u : 0u) |
                 (m3.x ? 0x1000u : 0u) | (m3.y ? 0x2000u : 0u) |
                 (m3.z ? 0x4000u : 0u) | (m3.w ? 0x8000u : 0u);
      }

      // -- pass 1: WLS sums ------------------------------------------
      float sw = 0.f, swx = 0.f, swy = 0.f, swxx = 0.f, swxy = 0.f;
      float msum = 0.f, symsum = 0.f;
#define P1(xx_, yy_, bit_)                                                   \
  {                                                                          \
    const float m = (mbits >> (bit_)) & 1u ? 1.f : 0.f;                      \
    const float xx = (xx_), yy = (yy_);                                      \
    const float w = m * frcp(fmaxf(yy, 1e-5f));                              \
    const float wx = w * xx;                                                 \
    sw += w; swx += wx; swy = fmaf(w, yy, swy);                              \
    swxx = fmaf(wx, xx, swxx); swxy = fmaf(wx, yy, swxy);                    \
    msum += m; symsum = fmaf(m, yy, symsum);                                 \
  }
      P1(xa0.x, ya0.x, 0)  P1(xa0.y, ya0.y, 1)
      P1(xa0.z, ya0.z, 2)  P1(xa0.w, ya0.w, 3)
      P1(xa1.x, ya1.x, 4)  P1(xa1.y, ya1.y, 5)
      P1(xa1.z, ya1.z, 6)  P1(xa1.w, ya1.w, 7)
      P1(xa2.x, ya2.x, 8)  P1(xa2.y, ya2.y, 9)
      P1(xa2.z, ya2.z, 10) P1(xa2.w, ya2.w, 11)
      P1(xa3.x, ya3.x, 12) P1(xa3.y, ya3.y, 13)
      P1(xa3.z, ya3.z, 14) P1(xa3.w, ya3.w, 15)
#undef P1
      sw = rowredu(sw); swx = rowredu(swx); swy = rowredu(swy);
      swxx = rowredu(swxx); swxy = rowredu(swxy);

      float det = sw * swxx - swx * swx;
      if (fabsf(det) < 1e-12f) det = 1e-12f;  // jnp.where -> +1e-12 any sign
      float rdet = frcp(det);
      const float s0 = (sw * swxy - swx * swy) * rdet;
      const float t0 = (swxx * swy - swx * swxy) * rdet;

      // -- pass 2: truncated refit; w recomputed (bit-identical) -------
      float sw2 = 0.f, swx2 = 0.f, swy2 = 0.f, swxx2 = 0.f, swxy2 = 0.f;
#define P2(xx_, yy_, bit_)                                                   \
  {                                                                          \
    const float m = (mbits >> (bit_)) & 1u ? 1.f : 0.f;                      \
    const float xx = (xx_), yy = (yy_);                                      \
    const float w = m * frcp(fmaxf(yy, 1e-5f));                              \
    const float e = w * fabsf(fmaf(s0, xx, t0) - yy);                        \
    const float w2 = (e < 1.0f) ? w : 0.f;                                   \
    const float w2x = w2 * xx;                                               \
    sw2 += w2; swx2 += w2x; swy2 = fmaf(w2, yy, swy2);                       \
    swxx2 = fmaf(w2x, xx, swxx2); swxy2 = fmaf(w2x, yy, swxy2);              \
  }
      P2(xa0.x, ya0.x, 0)  P2(xa0.y, ya0.y, 1)
      P2(xa0.z, ya0.z, 2)  P2(xa0.w, ya0.w, 3)
      P2(xa1.x, ya1.x, 4)  P2(xa1.y, ya1.y, 5)
      P2(xa1.z, ya1.z, 6)  P2(xa1.w, ya1.w, 7)
      P2(xa2.x, ya2.x, 8)  P2(xa2.y, ya2.y, 9)
      P2(xa2.z, ya2.z, 10) P2(xa2.w, ya2.w, 11)
      P2(xa3.x, ya3.x, 12) P2(xa3.y, ya3.y, 13)
      P2(xa3.z, ya3.z, 14) P2(xa3.w, ya3.w, 15)
#undef P2
      sw2 = rowredu(sw2); swx2 = rowredu(swx2); swy2 = rowredu(swy2);
      swxx2 = rowredu(swxx2); swxy2 = rowredu(swxy2);
      msum = rowredu(msum); symsum = rowredu(symsum);

      if (sw2 > 1e-8f) {  // sum(w2)==sw2; else fall back to pass-1 sums
        sw = sw2; swx = swx2; swy = swy2; swxx = swxx2; swxy = swxy2;
      }
      det = sw * swxx - swx * swx;
      if (fabsf(det) < 1e-12f) det = 1e-12f;
      rdet = frcp(det);
      const float s = (sw * swxy - swx * swy) * rdet;
      const float t = (swxx * swy - swx * swxy) * rdet;

      // -- pass 3: smooth-L1 patch loss --------------------------------
      const float mean_depth =
          (msum > 0.f) ? (symsum * frcp(fmaxf(msum, 1.f))) : 1.f;
      const float yfloor = 0.1f * mean_depth;

      float lsum = 0.f;
#define P3(xx_, yy_, bit_)                                                   \
  {                                                                          \
    const float m = (mbits >> (bit_)) & 1u ? 1.f : 0.f;                      \
    const float pw = m * frcp(fmaxf((yy_), yfloor));                         \
    const float err = fabsf(fmaf(s, (xx_), t) - (yy_)) * pw;                 \
    lsum += (err < 0.1f) ? (5.0f * err * err) : (err - 0.05f);               \
  }
      P3(xa0.x, ya0.x, 0)  P3(xa0.y, ya0.y, 1)
      P3(xa0.z, ya0.z, 2)  P3(xa0.w, ya0.w, 3)
      P3(xa1.x, ya1.x, 4)  P3(xa1.y, ya1.y, 5)
      P3(xa1.z, ya1.z, 6)  P3(xa1.w, ya1.w, 7)
      P3(xa2.x, ya2.x, 8)  P3(xa2.y, ya2.y, 9)
      P3(xa2.z, ya2.z, 10) P3(xa2.w, ya2.w, 11)
      P3(xa3.x, ya3.x, 12) P3(xa3.y, ya3.y, 13)
      P3(xa3.z, ya3.z, 14) P3(xa3.w, ya3.w, 15)
#undef P3
      const float patch_loss = rowredu(lsum) * invK;

      // -- validity (row-uniform), accumulate on col==0 ----------------
      const int pidx = row_ok ? patch : (total_patches - 1);
      const float gs = gsg[(unsigned)pidx / (unsigned)P];
      const float ratio = s * frcp(fmaxf(gs, 1e-12f));
      const bool gs_ok = (gs > 0.f) ? (ratio >= 0.1f && ratio <= 10.0f) : true;
      const bool valid = (msum * invK >= 0.3f) && (s > 0.f) && gs_ok;

      if (col == 0 && row_ok && valid) { wloss += patch_loss; wcnt += 1.f; }
    }
  } else {
    // ------- generic path (any K): wave-per-patch ---------------------
    const int wave_stride = gridDim.x * WPB;
    for (int patch = blockIdx.x * WPB + wib; patch < total_patches;
         patch += wave_stride) {
      const long base = (long)patch * (long)K;
      const float* xp = xg + base;
      const float* yp = yg + base;
      const int*   mp = mg + base;

      float sw = 0.f, swx = 0.f, swy = 0.f, swxx = 0.f, swxy = 0.f;
      float msum = 0.f, symsum = 0.f;
      for (int j = lane; j < K; j += 64) {
        const float m = mp[j] ? 1.f : 0.f;
        const float xx = xp[j], yy = yp[j];
        const float w = m * frcp(fmaxf(yy, 1e-5f));
        const float wx = w * xx;
        sw += w; swx += wx; swy = fmaf(w, yy, swy);
        swxx = fmaf(wx, xx, swxx); swxy = fmaf(wx, yy, swxy);
        msum += m; symsum = fmaf(m, yy, symsum);
      }
      sw = wredu(sw); swx = wredu(swx); swy = wredu(swy);
      swxx = wredu(swxx); swxy = wredu(swxy);
      msum = wredu(msum); symsum = wredu(symsum);

      float det = sw * swxx - swx * swx;
      if (fabsf(det) < 1e-12f) det = 1e-12f;
      float rdet = frcp(det);
      const float s0 = (sw * swxy - swx * swy) * rdet;
      const float t0 = (swxx * swy - swx * swxy) * rdet;

      float sw2 = 0.f, swx2 = 0.f, swy2 = 0.f, swxx2 = 0.f, swxy2 = 0.f;
      for (int j = lane; j < K; j += 64) {
        const float m = mp[j] ? 1.f : 0.f;
        const float xx = xp[j], yy = yp[j];
        const float w = m * frcp(fmaxf(yy, 1e-5f));
        const float e = w * fabsf(fmaf(s0, xx, t0) - yy);
        const float w2 = (e < 1.0f) ? w : 0.f;
        const float w2x = w2 * xx;
        sw2 += w2; swx2 += w2x; swy2 = fmaf(w2, yy, swy2);
        swxx2 = fmaf(w2x, xx, swxx2); swxy2 = fmaf(w2x, yy, swxy2);
      }
      sw2 = wredu(sw2); swx2 = wredu(swx2); swy2 = wredu(swy2);
      swxx2 = wredu(swxx2); swxy2 = wredu(swxy2);

      if (sw2 > 1e-8f) {
        sw = sw2; swx = swx2; swy = swy2; swxx = swxx2; swxy = swxy2;
      }
      det = sw * swxx - swx * swx;
      if (fabsf(det) < 1e-12f) det = 1e-12f;
      rdet = frcp(det);
      const float s = (sw * swxy - swx * swy) * rdet;
      const float t = (swxx * swy - swx * swxy) * rdet;

      const float mean_depth =
          (msum > 0.f) ? (symsum * frcp(fmaxf(msum, 1.f))) : 1.f;
      const float yfloor = 0.1f * mean_depth;

      float lsum = 0.f;
      for (int j = lane; j < K; j += 64) {
        const float m = mp[j] ? 1.f : 0.f;
        const float xx = xp[j], yy = yp[j];
        const float pw = m * frcp(fmaxf(yy, yfloor));
        const float err = fabsf(fmaf(s, xx, t) - yy) * pw;
        lsum += (err < 0.1f) ? (5.0f * err * err) : (err - 0.05f);
      }
      const float patch_loss = wredu(lsum) * invK;

      const float gs = gsg[(unsigned)patch / (unsigned)P];
      const float ratio = s * frcp(fmaxf(gs, 1e-12f));
      const bool gs_ok = (gs > 0.f) ? (ratio >= 0.1f && ratio <= 10.0f) : true;
      const bool valid = (msum * invK >= 0.3f) && (s > 0.f) && gs_ok;

      if (lane == 0 && valid) { wloss += patch_loss; wcnt += 1.f; }
    }
  }

  // ---- wave reduce -> block reduce (LDS) -> plain store to OWN line --
  wloss = wredu(wloss);
  wcnt  = wredu(wcnt);
  __shared__ float sl[WPB], sc[WPB];
  if (lane == 0) { sl[wib] = wloss; sc[wib] = wcnt; }
  __syncthreads();
  if (threadIdx.x == 0) {
    float bl = 0.f, bc = 0.f;
    #pragma unroll
    for (int i = 0; i < WPB; ++i) { bl += sl[i]; bc += sc[i]; }
    // private 128-B line per block: no zeroing, no atomics needed.
    ws[blockIdx.x * 32]     = bl;
    ws[blockIdx.x * 32 + 1] = bc;
  }
}

__global__ __launch_bounds__(256) void finalize_kernel(
    const float* __restrict__ ws, float* __restrict__ out, int nblocks) {
  const int lane = threadIdx.x & 63;
  const int wib  = threadIdx.x >> 6;
  float l = 0.f, c = 0.f;
  for (int i = threadIdx.x; i < nblocks; i += 256) {
    l += ws[i * 32];
    c += ws[i * 32 + 1];
  }
  l = wredu(l); c = wredu(c);
  __shared__ float sl[4], sc[4];
  if (lane == 0) { sl[wib] = l; sc[wib] = c; }
  __syncthreads();
  if (threadIdx.x == 0) {
    const float L = sl[0] + sl[1] + sl[2] + sl[3];
    const float C = sc[0] + sc[1] + sc[2] + sc[3];
    out[0] = (C > 0.f) ? (L / fmaxf(C, 1.f)) : 0.f;
  }
}

extern "C" void kernel_launch(void* const* d_in, const int* in_sizes, int n_in,
                              void* d_out, int out_size, void* d_ws, size_t ws_size,
                              hipStream_t stream) {
  const float* pred = (const float*)d_in[0];
  const float* gt   = (const float*)d_in[1];
  const int*   mask = (const int*)d_in[2];
  const float* gs   = (const float*)d_in[3];
  const int*   pP   = (const int*)d_in[4];
  const int*   pK   = (const int*)d_in[5];
  const int B = in_sizes[3];
  const long total_pixels = (long)in_sizes[0];
  float* ws = (float*)d_ws;

  // grid sized for K=256: 16 patches per block (4 waves x 4 rows)
  long est_patches = total_pixels / 256;
  long blocks = (est_patches + WPB * PPW - 1) / (WPB * PPW);
  if (blocks < 1) blocks = 1;
  if (blocks > MAXBLK) blocks = MAXBLK;
  moge_patch_kernel<<<(int)blocks, 256, 0, stream>>>(pred, gt, mask, gs, pP,
                                                     pK, B, ws);
  finalize_kernel<<<1, 256, 0, stream>>>(ws, (float*)d_out, (int)blocks);
}